// Round 1
// baseline (222.979 us; speedup 1.0000x reference)
//
#include <hip/hip_runtime.h>
#include <stdint.h>

typedef __bf16 bf16;
typedef __bf16 bf16x4_t __attribute__((ext_vector_type(4)));
typedef __bf16 bf16x8_t __attribute__((ext_vector_type(8)));
typedef float f32x4 __attribute__((ext_vector_type(4)));

static constexpr int NB = 2, SS = 2048, DD = 1024, NH = 16, HD = 64;

__device__ __forceinline__ void gl_lds16(const void* g, void* l) {
    __builtin_amdgcn_global_load_lds((__attribute__((address_space(1))) void*)g,
                                     (__attribute__((address_space(3))) void*)l, 16, 0, 0);
}

// ---------------- fused fp32 -> bf16 cast of h + Wq + Wk + Wv + Wo ----------------
__global__ __launch_bounds__(256) void cast_all(const float* __restrict__ h,
                                                const float* __restrict__ Wq,
                                                const float* __restrict__ Wk,
                                                const float* __restrict__ Wv,
                                                const float* __restrict__ Wo,
                                                bf16* __restrict__ dst) {
    int i = blockIdx.x * 256 + threadIdx.x;  // float4 index, grid covers exactly 2097152
    const float* src;
    int off;
    if (i < 1048576) { src = h; off = i; }
    else {
        int r = i - 1048576;
        int w = r >> 18;
        off = r & 262143;
        src = (w == 0) ? Wq : (w == 1) ? Wk : (w == 2) ? Wv : Wo;
    }
    float4 v = reinterpret_cast<const float4*>(src)[off];
    bf16x4_t o;
    o.x = (bf16)v.x; o.y = (bf16)v.y; o.z = (bf16)v.z; o.w = (bf16)v.w;
    reinterpret_cast<bf16x4_t*>(dst)[i] = o;
}

// ---------------- 128x128 NT-GEMM mainloop (m97 structure) ----------------
__device__ __forceinline__ void gemm128_mainloop(const bf16* __restrict__ Ablk,
                                                 const bf16* __restrict__ Bblk,
                                                 int K, f32x4 acc[4][4]) {
    __shared__ __align__(16) bf16 As[128 * 32];
    __shared__ __align__(16) bf16 Bs[128 * 32];
    const int tid = threadIdx.x;
    const int wave = tid >> 6, lane = tid & 63;
    const int quad = lane >> 4, l15 = lane & 15;
    const int wm = wave >> 1, wn = wave & 1;

#pragma unroll
    for (int mi = 0; mi < 4; mi++)
#pragma unroll
        for (int ni = 0; ni < 4; ni++) {
            acc[mi][ni][0] = 0.f; acc[mi][ni][1] = 0.f;
            acc[mi][ni][2] = 0.f; acc[mi][ni][3] = 0.f;
        }

    const int n0c = tid;
    const int r0 = n0c >> 2, c0 = (n0c & 3) ^ ((r0 >> 1) & 3);
    const int n1c = 256 + tid;
    const int r1 = n1c >> 2, c1 = (n1c & 3) ^ ((r1 >> 1) & 3);

    for (int kk = 0; kk < K; kk += 32) {
        __syncthreads();
        gl_lds16(Ablk + (size_t)r0 * K + kk + c0 * 8, &As[(wave * 64) * 8]);
        gl_lds16(Ablk + (size_t)r1 * K + kk + c1 * 8, &As[(256 + wave * 64) * 8]);
        gl_lds16(Bblk + (size_t)r0 * K + kk + c0 * 8, &Bs[(wave * 64) * 8]);
        gl_lds16(Bblk + (size_t)r1 * K + kk + c1 * 8, &Bs[(256 + wave * 64) * 8]);
        __syncthreads();

        bf16x8_t a[4], b[4];
#pragma unroll
        for (int mi = 0; mi < 4; mi++) {
            int R = wm * 64 + mi * 16 + l15;
            a[mi] = *(const bf16x8_t*)&As[R * 32 + ((quad ^ ((R >> 1) & 3)) << 3)];
        }
#pragma unroll
        for (int ni = 0; ni < 4; ni++) {
            int R = wn * 64 + ni * 16 + l15;
            b[ni] = *(const bf16x8_t*)&Bs[R * 32 + ((quad ^ ((R >> 1) & 3)) << 3)];
        }
#pragma unroll
        for (int mi = 0; mi < 4; mi++)
#pragma unroll
            for (int ni = 0; ni < 4; ni++)
                acc[mi][ni] = __builtin_amdgcn_mfma_f32_16x16x32_bf16(a[mi], b[ni], acc[mi][ni], 0, 0, 0);
    }
}

// ---------------- 64x128 NT-GEMM mainloop ----------------
__device__ __forceinline__ void gemm64_mainloop(const bf16* __restrict__ Ablk,
                                                const bf16* __restrict__ Bblk,
                                                int K, f32x4 acc[2][4]) {
    __shared__ __align__(16) bf16 As[64 * 32];
    __shared__ __align__(16) bf16 Bs[128 * 32];
    const int tid = threadIdx.x;
    const int wave = tid >> 6, lane = tid & 63;
    const int quad = lane >> 4, l15 = lane & 15;
    const int wm = wave >> 1, wn = wave & 1;

#pragma unroll
    for (int mi = 0; mi < 2; mi++)
#pragma unroll
        for (int ni = 0; ni < 4; ni++) {
            acc[mi][ni][0] = 0.f; acc[mi][ni][1] = 0.f;
            acc[mi][ni][2] = 0.f; acc[mi][ni][3] = 0.f;
        }

    const int ra = tid >> 2, ca = (tid & 3) ^ ((ra >> 1) & 3);
    const int r0 = tid >> 2, c0 = (tid & 3) ^ ((r0 >> 1) & 3);
    const int n1c = 256 + tid;
    const int r1 = n1c >> 2, c1 = (n1c & 3) ^ ((r1 >> 1) & 3);

    for (int kk = 0; kk < K; kk += 32) {
        __syncthreads();
        gl_lds16(Ablk + (size_t)ra * K + kk + ca * 8, &As[(wave * 64) * 8]);
        gl_lds16(Bblk + (size_t)r0 * K + kk + c0 * 8, &Bs[(wave * 64) * 8]);
        gl_lds16(Bblk + (size_t)r1 * K + kk + c1 * 8, &Bs[(256 + wave * 64) * 8]);
        __syncthreads();

        bf16x8_t a[2], b[4];
#pragma unroll
        for (int mi = 0; mi < 2; mi++) {
            int R = wm * 32 + mi * 16 + l15;
            a[mi] = *(const bf16x8_t*)&As[R * 32 + ((quad ^ ((R >> 1) & 3)) << 3)];
        }
#pragma unroll
        for (int ni = 0; ni < 4; ni++) {
            int R = wn * 64 + ni * 16 + l15;
            b[ni] = *(const bf16x8_t*)&Bs[R * 32 + ((quad ^ ((R >> 1) & 3)) << 3)];
        }
#pragma unroll
        for (int mi = 0; mi < 2; mi++)
#pragma unroll
            for (int ni = 0; ni < 4; ni++)
                acc[mi][ni] = __builtin_amdgcn_mfma_f32_16x16x32_bf16(a[mi], b[ni], acc[mi][ni], 0, 0, 0);
    }
}

// ---------------- QKV projection ----------------
// Q pre-scaled by 0.125*log2(e). V stored TRANSPOSED: Vb[bh][hd][s] so the
// attention kernel can read V^T fragments directly (no in-kernel transpose).
__global__ __launch_bounds__(256) void gemm_qkv(const bf16* __restrict__ A, const bf16* __restrict__ Wqkv,
                                                const float* __restrict__ bq, const float* __restrict__ bk,
                                                const float* __restrict__ bv,
                                                bf16* __restrict__ Qb, bf16* __restrict__ Kb, bf16* __restrict__ Vb) {
    const int m0 = blockIdx.x * 128;
    const int n0 = blockIdx.y * 128;
    f32x4 acc[4][4];
    gemm128_mainloop(A + (size_t)m0 * DD, Wqkv + (size_t)n0 * DD, DD, acc);

    const int tid = threadIdx.x, wave = tid >> 6, lane = tid & 63;
    const int quad = lane >> 4, l15 = lane & 15;
    const int wm = wave >> 1, wn = wave & 1;

    const int which = n0 >> 10;
    const float* bias = (which == 0) ? bq : (which == 1) ? bk : bv;
    const float sc = (which == 0) ? 0.18033688f : 1.0f;  // 0.125 * log2(e)

    const int cbase = (n0 & 1023) + wn * 64;
    const int head = cbase >> 6;
    const int bb = m0 >> 11;
    const int s0 = (m0 & 2047) + wm * 64;

    if (which == 2) {
        // V: transposed store [bh][hd][S], bf16x4 (4 consecutive s) per (mi,ni)
        bf16* dbase = Vb + ((size_t)(bb * NH + head)) * HD * SS;
#pragma unroll
        for (int ni = 0; ni < 4; ni++) {
            float bsv = bias[cbase + ni * 16 + l15];
            int hd = ni * 16 + l15;
#pragma unroll
            for (int mi = 0; mi < 4; mi++) {
                bf16x4_t pb;
                pb.x = (bf16)(acc[mi][ni][0] + bsv);
                pb.y = (bf16)(acc[mi][ni][1] + bsv);
                pb.z = (bf16)(acc[mi][ni][2] + bsv);
                pb.w = (bf16)(acc[mi][ni][3] + bsv);
                int s = s0 + mi * 16 + quad * 4;
                *(bf16x4_t*)&dbase[(size_t)hd * SS + s] = pb;
            }
        }
    } else {
        bf16* dst = (which == 0) ? Qb : Kb;
        bf16* dbase = dst + ((size_t)(bb * NH + head)) * SS * HD;
#pragma unroll
        for (int ni = 0; ni < 4; ni++) {
            float bsv = bias[cbase + ni * 16 + l15];
            int hd = ni * 16 + l15;
#pragma unroll
            for (int mi = 0; mi < 4; mi++) {
#pragma unroll
                for (int r = 0; r < 4; r++) {
                    int s = s0 + mi * 16 + quad * 4 + r;
                    dbase[(size_t)s * HD + hd] = (bf16)((acc[mi][ni][r] + bsv) * sc);
                }
            }
        }
    }
}

// ---------------- output projection: fp32 out, 64x128 tiles ----------------
__global__ __launch_bounds__(256) void gemm_out(const bf16* __restrict__ A, const bf16* __restrict__ Wo,
                                                const float* __restrict__ bo, float* __restrict__ out) {
    const int m0 = blockIdx.x * 64, n0 = blockIdx.y * 128;
    f32x4 acc[2][4];
    gemm64_mainloop(A + (size_t)m0 * DD, Wo + (size_t)n0 * DD, DD, acc);

    const int tid = threadIdx.x, wave = tid >> 6, lane = tid & 63;
    const int quad = lane >> 4, l15 = lane & 15;
    const int wm = wave >> 1, wn = wave & 1;
    float* obase = out + (size_t)(m0 + wm * 32) * DD + n0 + wn * 64;
#pragma unroll
    for (int ni = 0; ni < 4; ni++) {
        float bias = bo[n0 + wn * 64 + ni * 16 + l15];
#pragma unroll
        for (int mi = 0; mi < 2; mi++)
#pragma unroll
            for (int r = 0; r < 4; r++)
                obase[(size_t)(mi * 16 + quad * 4 + r) * DD + ni * 16 + l15] = acc[mi][ni][r] + bias;
    }
}

// ---------------- causal flash attention: barrier-free, L2-direct K/V ----------------
// bh = bx&31 -> head h always on XCD h%8: K+V = 2 MB/XCD, fully L2-resident.
// K-frags and V^T-frags are read DIRECTLY from global (L2 hit ~200cyc) instead
// of LDS staging (m169 lesson: staging L2-fit data is pure overhead). The only
// LDS left is the per-wave P strip -> NO __syncthreads anywhere in the main
// loop; waves slip independently and hide each other's latency.
// Online softmax uses defer-rescale (T13, THR=8 in log2 domain): the O-rescale
// pass is skipped unless the running max grows by >8 (P bounded by 2^8, f32
// accumulators have headroom). s_setprio(1) wraps both MFMA clusters (T5).
__global__ __launch_bounds__(256, 3) void attn_kernel(const bf16* __restrict__ Qb, const bf16* __restrict__ Kb,
                                                      const bf16* __restrict__ Vb, bf16* __restrict__ Ob,
                                                      bf16* __restrict__ Opart, float* __restrict__ Ml) {
    // descending lengths: 10x8, 2x7, 2x6, 2x5, 2x4, 2x3, 2x2, 2x1 (sum 136/bh)
    constexpr int PQ[24]  = {15,14,13,12,11,10, 9, 8, 15, 7, 14, 6, 13, 5, 12, 4, 11, 3, 10, 2,  9, 1,  8, 0};
    constexpr int PJ0[24] = { 0, 0, 0, 0, 0, 0, 0, 0,  8, 0,  8, 0,  8, 0,  8, 0,  8, 0,  8, 0,  8, 0,  8, 0};
    constexpr int PJ1[24] = { 8, 8, 8, 8, 8, 8, 8, 8, 16, 8, 15, 7, 14, 6, 13, 5, 12, 4, 11, 3, 10, 2,  9, 1};

    __shared__ __align__(16) bf16 Pt[4 * 32 * 64]; // per-wave P strips, XOR-swizzled (16 KB total)

    const int tid = threadIdx.x, wave = tid >> 6, lane = tid & 63;
    const int quad = lane >> 4, l15 = lane & 15;
    const int bx = blockIdx.x;
    const int p = bx >> 5, bh = bx & 31;
    const int qtile = PQ[p], jbeg = PJ0[p], jend = PJ1[p];
    const bool diagpart = (jend == qtile + 1);
    const size_t hoff = (size_t)bh * SS * HD;   // Q/K layout [bh][s][hd]
    const bf16* Qg = Qb + hoff + (size_t)qtile * 128 * HD;
    const bf16* Kh = Kb + hoff;
    const bf16* Vbase = Vb + (size_t)bh * HD * SS;  // V layout [bh][hd][s]
    bf16* Pw = &Pt[wave * 2048];

    // Q B-frags (already scaled by 0.125*log2e)
    bf16x8_t qf[2][2];
#pragma unroll
    for (int qt = 0; qt < 2; qt++)
#pragma unroll
        for (int ks = 0; ks < 2; ks++)
            qf[qt][ks] = *(const bf16x8_t*)(Qg + (wave * 32 + qt * 16 + l15) * HD + ks * 32 + quad * 8);

    f32x4 o[2][4];
#pragma unroll
    for (int qt = 0; qt < 2; qt++)
#pragma unroll
        for (int nO = 0; nO < 4; nO++) {
            o[qt][nO][0] = 0.f; o[qt][nO][1] = 0.f; o[qt][nO][2] = 0.f; o[qt][nO][3] = 0.f;
        }
    float mrow[2] = {-__builtin_inff(), -__builtin_inff()};
    float lrow[2] = {0.f, 0.f};

    for (int j = jbeg; j < jend; j++) {
        const bf16* Kg = Kh + (size_t)j * 128 * HD;
        const bf16* Vg = Vbase + j * 128;
        const bool diag = diagpart && (j == jend - 1);
#pragma unroll 1
        for (int kh = 0; kh < 2; kh++) {
            if (diag && kh == 1 && wave < 2) break;  // rows 0..63 fully masked vs keys 64..127

            // S^T = K * Q^T : st[kt][qt], key = kh*64 + kt*16 + quad*4 + r, qrow = qt*16 + l15
            f32x4 st[4][2];
#pragma unroll
            for (int kt = 0; kt < 4; kt++)
#pragma unroll
                for (int qt = 0; qt < 2; qt++) {
                    st[kt][qt][0] = 0.f; st[kt][qt][1] = 0.f; st[kt][qt][2] = 0.f; st[kt][qt][3] = 0.f;
                }
            __builtin_amdgcn_s_setprio(1);
#pragma unroll
            for (int ks = 0; ks < 2; ks++) {
#pragma unroll
                for (int kt = 0; kt < 4; kt++) {
                    int R = (kh * 4 + kt) * 16 + l15;
                    // K-frag direct from L2-resident global: row=key, 16B chunk (ks,quad)
                    bf16x8_t kf = *(const bf16x8_t*)(Kg + (size_t)R * HD + (ks << 5) + (quad << 3));
#pragma unroll
                    for (int qt = 0; qt < 2; qt++)
                        st[kt][qt] = __builtin_amdgcn_mfma_f32_16x16x32_bf16(kf, qf[qt][ks], st[kt][qt], 0, 0, 0);
                }
            }
            __builtin_amdgcn_s_setprio(0);
            if (diag) {
#pragma unroll
                for (int kt = 0; kt < 4; kt++)
#pragma unroll
                    for (int qt = 0; qt < 2; qt++)
#pragma unroll
                        for (int r = 0; r < 4; r++) {
                            int key = kh * 64 + kt * 16 + quad * 4 + r;
                            int row = wave * 32 + qt * 16 + l15;
                            if (key > row) st[kt][qt][r] = -__builtin_inff();
                        }
            }

            // online softmax (log2 domain) with defer-rescale (THR=8)
#pragma unroll
            for (int qt = 0; qt < 2; qt++) {
                float mx = -__builtin_inff();
#pragma unroll
                for (int kt = 0; kt < 4; kt++)
#pragma unroll
                    for (int r = 0; r < 4; r++) mx = fmaxf(mx, st[kt][qt][r]);
                mx = fmaxf(mx, __shfl_xor(mx, 16));
                mx = fmaxf(mx, __shfl_xor(mx, 32));
                if (!__all(mx <= mrow[qt] + 8.f)) {
                    float mnew = fmaxf(mrow[qt], mx);
                    float alpha = exp2f(mrow[qt] - mnew);
                    mrow[qt] = mnew;
                    lrow[qt] *= alpha;
#pragma unroll
                    for (int r = 0; r < 4; r++) {
                        float a = __shfl(alpha, (lane & 48) | (quad * 4 + r));
#pragma unroll
                        for (int nO = 0; nO < 4; nO++) o[qt][nO][r] *= a;
                    }
                }
                float sum = 0.f;
                const int row = qt * 16 + l15;
#pragma unroll
                for (int kt = 0; kt < 4; kt++) {
                    float p0 = exp2f(st[kt][qt][0] - mrow[qt]);
                    float p1 = exp2f(st[kt][qt][1] - mrow[qt]);
                    float p2 = exp2f(st[kt][qt][2] - mrow[qt]);
                    float p3 = exp2f(st[kt][qt][3] - mrow[qt]);
                    sum += (p0 + p1) + (p2 + p3);
                    bf16x4_t pb;
                    pb.x = (bf16)p0; pb.y = (bf16)p1; pb.z = (bf16)p2; pb.w = (bf16)p3;
                    int c = kt * 2 + (quad >> 1);
                    *(bf16x4_t*)&Pw[row * 64 + ((c ^ (row & 7)) << 3) + ((quad & 1) << 2)] = pb;
                }
                sum += __shfl_xor(sum, 16);
                sum += __shfl_xor(sum, 32);
                lrow[qt] += sum;
            }

            // O += P * V^T-frags (V^T direct from L2-resident global, pre-transposed layout)
#pragma unroll
            for (int ks = 0; ks < 2; ks++) {
                bf16x8_t pf[2];
#pragma unroll
                for (int qt = 0; qt < 2; qt++) {
                    int row = qt * 16 + l15;
                    int c = (ks << 2) | quad;
                    pf[qt] = *(const bf16x8_t*)&Pw[row * 64 + ((c ^ (row & 7)) << 3)];
                }
                __builtin_amdgcn_s_setprio(1);
#pragma unroll
                for (int nO = 0; nO < 4; nO++) {
                    int c = kh * 8 + ks * 4 + quad;  // 16-B key-chunk within V^T row
                    bf16x8_t vf = *(const bf16x8_t*)(Vg + (size_t)(nO * 16 + l15) * SS + (c << 3));
#pragma unroll
                    for (int qt = 0; qt < 2; qt++)
                        o[qt][nO] = __builtin_amdgcn_mfma_f32_16x16x32_bf16(pf[qt], vf, o[qt][nO], 0, 0, 0);
                }
                __builtin_amdgcn_s_setprio(0);
            }
        }
    }

    const int bb = bh >> 4, hh = bh & 15;
    if (qtile >= 8) {
        // split part: write unnormalized O (bf16) + m,l (f32)
        const int pidx = ((bh << 3) + (qtile - 8)) * 2 + (jbeg != 0 ? 1 : 0);
        bf16* Op = Opart + (size_t)pidx * (128 * 64);
        float* mlp = Ml + (size_t)pidx * 256;
#pragma unroll
        for (int qt = 0; qt < 2; qt++) {
            if (quad == 0) {
                mlp[wave * 32 + qt * 16 + l15] = mrow[qt];
                mlp[128 + wave * 32 + qt * 16 + l15] = lrow[qt];
            }
#pragma unroll
            for (int r = 0; r < 4; r++) {
                int row = wave * 32 + qt * 16 + quad * 4 + r;
#pragma unroll
                for (int nO = 0; nO < 4; nO++)
                    Op[row * 64 + nO * 16 + l15] = (bf16)o[qt][nO][r];
            }
        }
    } else {
        // whole tile: normalize and write Ob [B, S, H*64]
#pragma unroll
        for (int qt = 0; qt < 2; qt++) {
#pragma unroll
            for (int r = 0; r < 4; r++) {
                float linv = 1.f / __shfl(lrow[qt], (lane & 48) | (quad * 4 + r));
                int srow = qtile * 128 + wave * 32 + qt * 16 + quad * 4 + r;
#pragma unroll
                for (int nO = 0; nO < 4; nO++)
                    Ob[((size_t)(bb * SS + srow)) * DD + hh * HD + nO * 16 + l15] = (bf16)(o[qt][nO][r] * linv);
            }
        }
    }
}

// ---------------- merge two KV-half partials -> Ob (qtiles 8..15) ----------------
__global__ __launch_bounds__(256) void merge_kernel(const bf16* __restrict__ Opart,
                                                    const float* __restrict__ Ml,
                                                    bf16* __restrict__ Ob) {
    const int bh = blockIdx.x >> 3, q8 = blockIdx.x & 7;  // qtile = 8 + q8
    const int p0 = ((bh << 3) + q8) * 2, p1 = p0 + 1;
    const int t = threadIdx.x, row = t >> 1, c0 = (t & 1) * 32;
    float m0 = Ml[p0 * 256 + row], l0 = Ml[p0 * 256 + 128 + row];
    float m1 = Ml[p1 * 256 + row], l1 = Ml[p1 * 256 + 128 + row];
    float M = fmaxf(m0, m1);
    float w0 = exp2f(m0 - M), w1 = exp2f(m1 - M);
    float inv = 1.f / (l0 * w0 + l1 * w1);
    w0 *= inv; w1 *= inv;
    const bf16* O0 = Opart + (size_t)p0 * (128 * 64) + row * 64 + c0;
    const bf16* O1 = Opart + (size_t)p1 * (128 * 64) + row * 64 + c0;
    const int bb = bh >> 4, hh = bh & 15;
    const int srow = (8 + q8) * 128 + row;
    bf16* dst = Ob + ((size_t)(bb * SS + srow)) * DD + hh * HD + c0;
#pragma unroll
    for (int i = 0; i < 4; i++) {
        bf16x8_t a = *(const bf16x8_t*)(O0 + i * 8);
        bf16x8_t b = *(const bf16x8_t*)(O1 + i * 8);
        bf16x8_t r;
#pragma unroll
        for (int jj = 0; jj < 8; jj++)
            r[jj] = (bf16)((float)a[jj] * w0 + (float)b[jj] * w1);
        *(bf16x8_t*)(dst + i * 8) = r;
    }
}

// ---------------- host launcher ----------------
extern "C" void kernel_launch(void* const* d_in, const int* in_sizes, int n_in,
                              void* d_out, int out_size, void* d_ws, size_t ws_size,
                              hipStream_t stream) {
    (void)in_sizes; (void)n_in; (void)out_size; (void)ws_size;
    const float* h  = (const float*)d_in[0];
    const float* Wq = (const float*)d_in[1];
    const float* bq = (const float*)d_in[2];
    const float* Wk = (const float*)d_in[3];
    const float* bk = (const float*)d_in[4];
    const float* Wv = (const float*)d_in[5];
    const float* bv = (const float*)d_in[6];
    const float* Wo = (const float*)d_in[7];
    const float* bo = (const float*)d_in[8];
    float* out = (float*)d_out;

    char* ws = (char*)d_ws;
    bf16* hbf  = (bf16*)(ws);                                  // 8,388,608  h bf16 (dead after gemm_qkv)
    bf16* wqkv = (bf16*)(ws + 8388608);                        // 6,291,456  Wq|Wk|Wv (dead after gemm_qkv)
    bf16* wo   = (bf16*)(ws + 8388608 + 6291456);              // 2,097,152  Wo
    bf16* Qb   = (bf16*)(ws + 16777216);                       // 8,388,608  [B,H,S,64] (scaled)
    bf16* Kb   = (bf16*)(ws + 16777216 + 8388608);             // [B,H,S,64]
    bf16* Vb   = (bf16*)(ws + 16777216 + 2 * 8388608);         // [B,H,64,S]  (transposed!)
    bf16* Ob   = (bf16*)(ws + 16777216 + 3 * 8388608);         // [B,S,H*64]
    // attention scratch reuses the dead cast region:
    bf16*  Opart = (bf16*)(ws);                                // 512 x 128x64 bf16 = 8,388,608
    float* Ml    = (float*)(ws + 8388608);                     // 512 x 256 f32   =   524,288

    cast_all<<<8192, 256, 0, stream>>>(h, Wq, Wk, Wv, Wo, hbf);
    gemm_qkv<<<dim3(32, 24), 256, 0, stream>>>(hbf, wqkv, bq, bk, bv, Qb, Kb, Vb);
    attn_kernel<<<768, 256, 0, stream>>>(Qb, Kb, Vb, Ob, Opart, Ml);
    merge_kernel<<<256, 256, 0, stream>>>(Opart, Ml, Ob);
    gemm_out<<<dim3(64, 8), 256, 0, stream>>>(Ob, wo, bo, out);
}

// Round 2
// 185.198 us; speedup vs baseline: 1.2040x; 1.2040x over previous
//
#include <hip/hip_runtime.h>
#include <stdint.h>

typedef __bf16 bf16;
typedef __bf16 bf16x4_t __attribute__((ext_vector_type(4)));
typedef __bf16 bf16x8_t __attribute__((ext_vector_type(8)));
typedef float f32x4 __attribute__((ext_vector_type(4)));

static constexpr int NB = 2, SS = 2048, DD = 1024, NH = 16, HD = 64;

__device__ __forceinline__ void gl_lds16(const void* g, void* l) {
    __builtin_amdgcn_global_load_lds((__attribute__((address_space(1))) void*)g,
                                     (__attribute__((address_space(3))) void*)l, 16, 0, 0);
}

// ---------------- fused fp32 -> bf16 cast of h + Wq + Wk + Wv + Wo ----------------
__global__ __launch_bounds__(256) void cast_all(const float* __restrict__ h,
                                                const float* __restrict__ Wq,
                                                const float* __restrict__ Wk,
                                                const float* __restrict__ Wv,
                                                const float* __restrict__ Wo,
                                                bf16* __restrict__ dst) {
    int i = blockIdx.x * 256 + threadIdx.x;  // float4 index, grid covers exactly 2097152
    const float* src;
    int off;
    if (i < 1048576) { src = h; off = i; }
    else {
        int r = i - 1048576;
        int w = r >> 18;
        off = r & 262143;
        src = (w == 0) ? Wq : (w == 1) ? Wk : (w == 2) ? Wv : Wo;
    }
    float4 v = reinterpret_cast<const float4*>(src)[off];
    bf16x4_t o;
    o.x = (bf16)v.x; o.y = (bf16)v.y; o.z = (bf16)v.z; o.w = (bf16)v.w;
    reinterpret_cast<bf16x4_t*>(dst)[i] = o;
}

// ---------------- 128x128 NT-GEMM mainloop (m97 structure) ----------------
__device__ __forceinline__ void gemm128_mainloop(const bf16* __restrict__ Ablk,
                                                 const bf16* __restrict__ Bblk,
                                                 int K, f32x4 acc[4][4]) {
    __shared__ __align__(16) bf16 As[128 * 32];
    __shared__ __align__(16) bf16 Bs[128 * 32];
    const int tid = threadIdx.x;
    const int wave = tid >> 6, lane = tid & 63;
    const int quad = lane >> 4, l15 = lane & 15;
    const int wm = wave >> 1, wn = wave & 1;

#pragma unroll
    for (int mi = 0; mi < 4; mi++)
#pragma unroll
        for (int ni = 0; ni < 4; ni++) {
            acc[mi][ni][0] = 0.f; acc[mi][ni][1] = 0.f;
            acc[mi][ni][2] = 0.f; acc[mi][ni][3] = 0.f;
        }

    const int n0c = tid;
    const int r0 = n0c >> 2, c0 = (n0c & 3) ^ ((r0 >> 1) & 3);
    const int n1c = 256 + tid;
    const int r1 = n1c >> 2, c1 = (n1c & 3) ^ ((r1 >> 1) & 3);

    for (int kk = 0; kk < K; kk += 32) {
        __syncthreads();
        gl_lds16(Ablk + (size_t)r0 * K + kk + c0 * 8, &As[(wave * 64) * 8]);
        gl_lds16(Ablk + (size_t)r1 * K + kk + c1 * 8, &As[(256 + wave * 64) * 8]);
        gl_lds16(Bblk + (size_t)r0 * K + kk + c0 * 8, &Bs[(wave * 64) * 8]);
        gl_lds16(Bblk + (size_t)r1 * K + kk + c1 * 8, &Bs[(256 + wave * 64) * 8]);
        __syncthreads();

        bf16x8_t a[4], b[4];
#pragma unroll
        for (int mi = 0; mi < 4; mi++) {
            int R = wm * 64 + mi * 16 + l15;
            a[mi] = *(const bf16x8_t*)&As[R * 32 + ((quad ^ ((R >> 1) & 3)) << 3)];
        }
#pragma unroll
        for (int ni = 0; ni < 4; ni++) {
            int R = wn * 64 + ni * 16 + l15;
            b[ni] = *(const bf16x8_t*)&Bs[R * 32 + ((quad ^ ((R >> 1) & 3)) << 3)];
        }
#pragma unroll
        for (int mi = 0; mi < 4; mi++)
#pragma unroll
            for (int ni = 0; ni < 4; ni++)
                acc[mi][ni] = __builtin_amdgcn_mfma_f32_16x16x32_bf16(a[mi], b[ni], acc[mi][ni], 0, 0, 0);
    }
}

// ---------------- 64x128 NT-GEMM mainloop ----------------
__device__ __forceinline__ void gemm64_mainloop(const bf16* __restrict__ Ablk,
                                                const bf16* __restrict__ Bblk,
                                                int K, f32x4 acc[2][4]) {
    __shared__ __align__(16) bf16 As[64 * 32];
    __shared__ __align__(16) bf16 Bs[128 * 32];
    const int tid = threadIdx.x;
    const int wave = tid >> 6, lane = tid & 63;
    const int quad = lane >> 4, l15 = lane & 15;
    const int wm = wave >> 1, wn = wave & 1;

#pragma unroll
    for (int mi = 0; mi < 2; mi++)
#pragma unroll
        for (int ni = 0; ni < 4; ni++) {
            acc[mi][ni][0] = 0.f; acc[mi][ni][1] = 0.f;
            acc[mi][ni][2] = 0.f; acc[mi][ni][3] = 0.f;
        }

    const int ra = tid >> 2, ca = (tid & 3) ^ ((ra >> 1) & 3);
    const int r0 = tid >> 2, c0 = (tid & 3) ^ ((r0 >> 1) & 3);
    const int n1c = 256 + tid;
    const int r1 = n1c >> 2, c1 = (n1c & 3) ^ ((r1 >> 1) & 3);

    for (int kk = 0; kk < K; kk += 32) {
        __syncthreads();
        gl_lds16(Ablk + (size_t)ra * K + kk + ca * 8, &As[(wave * 64) * 8]);
        gl_lds16(Bblk + (size_t)r0 * K + kk + c0 * 8, &Bs[(wave * 64) * 8]);
        gl_lds16(Bblk + (size_t)r1 * K + kk + c1 * 8, &Bs[(256 + wave * 64) * 8]);
        __syncthreads();

        bf16x8_t a[2], b[4];
#pragma unroll
        for (int mi = 0; mi < 2; mi++) {
            int R = wm * 32 + mi * 16 + l15;
            a[mi] = *(const bf16x8_t*)&As[R * 32 + ((quad ^ ((R >> 1) & 3)) << 3)];
        }
#pragma unroll
        for (int ni = 0; ni < 4; ni++) {
            int R = wn * 64 + ni * 16 + l15;
            b[ni] = *(const bf16x8_t*)&Bs[R * 32 + ((quad ^ ((R >> 1) & 3)) << 3)];
        }
#pragma unroll
        for (int mi = 0; mi < 2; mi++)
#pragma unroll
            for (int ni = 0; ni < 4; ni++)
                acc[mi][ni] = __builtin_amdgcn_mfma_f32_16x16x32_bf16(a[mi], b[ni], acc[mi][ni], 0, 0, 0);
    }
}

// ---------------- QKV projection ----------------
// Q pre-scaled by 0.125*log2(e). V stored TRANSPOSED: Vb[bh][hd][s] so the
// attention kernel can DMA-stage V^T directly (no in-kernel transpose).
__global__ __launch_bounds__(256) void gemm_qkv(const bf16* __restrict__ A, const bf16* __restrict__ Wqkv,
                                                const float* __restrict__ bq, const float* __restrict__ bk,
                                                const float* __restrict__ bv,
                                                bf16* __restrict__ Qb, bf16* __restrict__ Kb, bf16* __restrict__ Vb) {
    const int m0 = blockIdx.x * 128;
    const int n0 = blockIdx.y * 128;
    f32x4 acc[4][4];
    gemm128_mainloop(A + (size_t)m0 * DD, Wqkv + (size_t)n0 * DD, DD, acc);

    const int tid = threadIdx.x, wave = tid >> 6, lane = tid & 63;
    const int quad = lane >> 4, l15 = lane & 15;
    const int wm = wave >> 1, wn = wave & 1;

    const int which = n0 >> 10;
    const float* bias = (which == 0) ? bq : (which == 1) ? bk : bv;
    const float sc = (which == 0) ? 0.18033688f : 1.0f;  // 0.125 * log2(e)

    const int cbase = (n0 & 1023) + wn * 64;
    const int head = cbase >> 6;
    const int bb = m0 >> 11;
    const int s0 = (m0 & 2047) + wm * 64;

    if (which == 2) {
        // V: transposed store [bh][hd][S], bf16x4 (4 consecutive s) per (mi,ni)
        bf16* dbase = Vb + ((size_t)(bb * NH + head)) * HD * SS;
#pragma unroll
        for (int ni = 0; ni < 4; ni++) {
            float bsv = bias[cbase + ni * 16 + l15];
            int hd = ni * 16 + l15;
#pragma unroll
            for (int mi = 0; mi < 4; mi++) {
                bf16x4_t pb;
                pb.x = (bf16)(acc[mi][ni][0] + bsv);
                pb.y = (bf16)(acc[mi][ni][1] + bsv);
                pb.z = (bf16)(acc[mi][ni][2] + bsv);
                pb.w = (bf16)(acc[mi][ni][3] + bsv);
                int s = s0 + mi * 16 + quad * 4;
                *(bf16x4_t*)&dbase[(size_t)hd * SS + s] = pb;
            }
        }
    } else {
        bf16* dst = (which == 0) ? Qb : Kb;
        bf16* dbase = dst + ((size_t)(bb * NH + head)) * SS * HD;
#pragma unroll
        for (int ni = 0; ni < 4; ni++) {
            float bsv = bias[cbase + ni * 16 + l15];
            int hd = ni * 16 + l15;
#pragma unroll
            for (int mi = 0; mi < 4; mi++) {
#pragma unroll
                for (int r = 0; r < 4; r++) {
                    int s = s0 + mi * 16 + quad * 4 + r;
                    dbase[(size_t)s * HD + hd] = (bf16)((acc[mi][ni][r] + bsv) * sc);
                }
            }
        }
    }
}

// ---------------- output projection: fp32 out, 64x128 tiles ----------------
__global__ __launch_bounds__(256) void gemm_out(const bf16* __restrict__ A, const bf16* __restrict__ Wo,
                                                const float* __restrict__ bo, float* __restrict__ out) {
    const int m0 = blockIdx.x * 64, n0 = blockIdx.y * 128;
    f32x4 acc[2][4];
    gemm64_mainloop(A + (size_t)m0 * DD, Wo + (size_t)n0 * DD, DD, acc);

    const int tid = threadIdx.x, wave = tid >> 6, lane = tid & 63;
    const int quad = lane >> 4, l15 = lane & 15;
    const int wm = wave >> 1, wn = wave & 1;
    float* obase = out + (size_t)(m0 + wm * 32) * DD + n0 + wn * 64;
#pragma unroll
    for (int ni = 0; ni < 4; ni++) {
        float bias = bo[n0 + wn * 64 + ni * 16 + l15];
#pragma unroll
        for (int mi = 0; mi < 2; mi++)
#pragma unroll
            for (int r = 0; r < 4; r++)
                obase[(size_t)(mi * 16 + quad * 4 + r) * DD + ni * 16 + l15] = acc[mi][ni][r] + bias;
    }
}

// ---------------- causal flash attention: half-tile double-buffered DMA pipeline ----------------
// bh = bx&31 -> head h always on XCD h%8 (K/V 2 MB/XCD, L2-resident).
// Round-1 lesson: direct-from-L2 K/V reads are latency-bound (MfmaUtil 13->8%).
// Staging via global_load_lds is required; the fix is overlapping it:
//   r0:  barrier -> issue DMA -> barrier(vmcnt0 drain) -> compute   (drain exposed)
//   now: issue DMA(half h+1) -> compute(half h) -> barrier          (drain overlapped)
// Double-buffer at 64-key half-tile granularity: 4 x 8KB K/V buffers + 16KB P
// = 48 KB -> keeps 3 blocks/CU. One barrier per half instead of two per tile.
// T13 defer-rescale (THR=8, log2 domain) + T5 setprio around MFMA clusters.
__global__ __launch_bounds__(256, 3) void attn_kernel(const bf16* __restrict__ Qb, const bf16* __restrict__ Kb,
                                                      const bf16* __restrict__ Vb, bf16* __restrict__ Ob,
                                                      bf16* __restrict__ Opart, float* __restrict__ Ml) {
    // descending lengths: 10x8, 2x7, 2x6, 2x5, 2x4, 2x3, 2x2, 2x1 (sum 136/bh)
    constexpr int PQ[24]  = {15,14,13,12,11,10, 9, 8, 15, 7, 14, 6, 13, 5, 12, 4, 11, 3, 10, 2,  9, 1,  8, 0};
    constexpr int PJ0[24] = { 0, 0, 0, 0, 0, 0, 0, 0,  8, 0,  8, 0,  8, 0,  8, 0,  8, 0,  8, 0,  8, 0,  8, 0};
    constexpr int PJ1[24] = { 8, 8, 8, 8, 8, 8, 8, 8, 16, 8, 15, 7, 14, 6, 13, 5, 12, 4, 11, 3, 10, 2,  9, 1};

    __shared__ __align__(16) bf16 Kt[2][64 * 64];   // K half-tiles, XOR-swizzled, DMA (8KB x2)
    __shared__ __align__(16) bf16 Vt[2][64 * 64];   // V^T half-tiles, XOR-swizzled, DMA (8KB x2)
    __shared__ __align__(16) bf16 Pt[4 * 32 * 64];  // per-wave P strips, XOR-swizzled (16KB)

    const int tid = threadIdx.x, wave = tid >> 6, lane = tid & 63;
    const int quad = lane >> 4, l15 = lane & 15;
    const int bx = blockIdx.x;
    const int p = bx >> 5, bh = bx & 31;
    const int qtile = PQ[p], jbeg = PJ0[p], jend = PJ1[p];
    const bool diagpart = (jend == qtile + 1);
    const size_t hoff = (size_t)bh * SS * HD;   // Q/K layout [bh][s][hd]
    const bf16* Qg = Qb + hoff + (size_t)qtile * 128 * HD;
    const bf16* Kbase = Kb + hoff;
    const bf16* Vbase = Vb + (size_t)bh * HD * SS;  // V layout [bh][hd][s]
    bf16* Pw = &Pt[wave * 2048];

    // Q B-frags (already scaled by 0.125*log2e)
    bf16x8_t qf[2][2];
#pragma unroll
    for (int qt = 0; qt < 2; qt++)
#pragma unroll
        for (int ks = 0; ks < 2; ks++)
            qf[qt][ks] = *(const bf16x8_t*)(Qg + (wave * 32 + qt * 16 + l15) * HD + ks * 32 + quad * 8);

    f32x4 o[2][4];
#pragma unroll
    for (int qt = 0; qt < 2; qt++)
#pragma unroll
        for (int nO = 0; nO < 4; nO++) {
            o[qt][nO][0] = 0.f; o[qt][nO][1] = 0.f; o[qt][nO][2] = 0.f; o[qt][nO][3] = 0.f;
        }
    float mrow[2] = {-__builtin_inff(), -__builtin_inff()};
    float lrow[2] = {0.f, 0.f};

    // stage one 64-key half (j, kh) into buffer buf: 2 K + 2 V DMA per thread
    auto STAGE = [&](int j, int kh, int buf) {
        const bf16* Kg = Kbase + ((size_t)j * 128 + kh * 64) * HD;
        const bf16* Vg = Vbase + j * 128 + kh * 64;
#pragma unroll
        for (int t = 0; t < 2; t++) {
            int n = t * 256 + tid;
            int row = n >> 3, gc = (n & 7) ^ (row & 7);
            gl_lds16(Kg + row * HD + gc * 8, &Kt[buf][(t * 256 + wave * 64) * 8]);
        }
#pragma unroll
        for (int t = 0; t < 2; t++) {
            int n = t * 256 + tid;
            int row = n >> 3, gc = (n & 7) ^ (row & 7);
            gl_lds16(Vg + (size_t)row * SS + gc * 8, &Vt[buf][(t * 256 + wave * 64) * 8]);
        }
    };

    const int nHalves = (jend - jbeg) * 2;
    STAGE(jbeg, 0, 0);
    __syncthreads();  // drain prologue DMA
    int cur = 0;

    for (int hh = 0; hh < nHalves; hh++) {
        const int j = jbeg + (hh >> 1), kh = hh & 1;
        // prefetch next half into the other buffer (overlaps with compute below)
        if (hh + 1 < nHalves) STAGE(jbeg + ((hh + 1) >> 1), (hh + 1) & 1, cur ^ 1);

        const bool diag = diagpart && (j == jend - 1);
        if (!(diag && kh == 1 && wave < 2)) {  // rows 0..63 fully masked vs keys 64..127
            // S^T = K * Q^T : st[kt][qt], key = kh*64 + kt*16 + quad*4 + r, qrow = qt*16 + l15
            f32x4 st[4][2];
#pragma unroll
            for (int kt = 0; kt < 4; kt++)
#pragma unroll
                for (int qt = 0; qt < 2; qt++) {
                    st[kt][qt][0] = 0.f; st[kt][qt][1] = 0.f; st[kt][qt][2] = 0.f; st[kt][qt][3] = 0.f;
                }
            __builtin_amdgcn_s_setprio(1);
#pragma unroll
            for (int ks = 0; ks < 2; ks++) {
#pragma unroll
                for (int kt = 0; kt < 4; kt++) {
                    int R = kt * 16 + l15;  // key row within half
                    bf16x8_t kf = *(const bf16x8_t*)&Kt[cur][R * 64 + ((((ks << 2) | quad) ^ (R & 7)) << 3)];
#pragma unroll
                    for (int qt = 0; qt < 2; qt++)
                        st[kt][qt] = __builtin_amdgcn_mfma_f32_16x16x32_bf16(kf, qf[qt][ks], st[kt][qt], 0, 0, 0);
                }
            }
            __builtin_amdgcn_s_setprio(0);
            if (diag) {
#pragma unroll
                for (int kt = 0; kt < 4; kt++)
#pragma unroll
                    for (int qt = 0; qt < 2; qt++)
#pragma unroll
                        for (int r = 0; r < 4; r++) {
                            int key = kh * 64 + kt * 16 + quad * 4 + r;
                            int row = wave * 32 + qt * 16 + l15;
                            if (key > row) st[kt][qt][r] = -__builtin_inff();
                        }
            }

            // online softmax (log2 domain) with defer-rescale (THR=8)
#pragma unroll
            for (int qt = 0; qt < 2; qt++) {
                float mx = -__builtin_inff();
#pragma unroll
                for (int kt = 0; kt < 4; kt++)
#pragma unroll
                    for (int r = 0; r < 4; r++) mx = fmaxf(mx, st[kt][qt][r]);
                mx = fmaxf(mx, __shfl_xor(mx, 16));
                mx = fmaxf(mx, __shfl_xor(mx, 32));
                if (!__all(mx <= mrow[qt] + 8.f)) {
                    float mnew = fmaxf(mrow[qt], mx);
                    float alpha = exp2f(mrow[qt] - mnew);
                    mrow[qt] = mnew;
                    lrow[qt] *= alpha;
#pragma unroll
                    for (int r = 0; r < 4; r++) {
                        float a = __shfl(alpha, (lane & 48) | (quad * 4 + r));
#pragma unroll
                        for (int nO = 0; nO < 4; nO++) o[qt][nO][r] *= a;
                    }
                }
                float sum = 0.f;
                const int row = qt * 16 + l15;
#pragma unroll
                for (int kt = 0; kt < 4; kt++) {
                    float p0 = exp2f(st[kt][qt][0] - mrow[qt]);
                    float p1 = exp2f(st[kt][qt][1] - mrow[qt]);
                    float p2 = exp2f(st[kt][qt][2] - mrow[qt]);
                    float p3 = exp2f(st[kt][qt][3] - mrow[qt]);
                    sum += (p0 + p1) + (p2 + p3);
                    bf16x4_t pb;
                    pb.x = (bf16)p0; pb.y = (bf16)p1; pb.z = (bf16)p2; pb.w = (bf16)p3;
                    int c = kt * 2 + (quad >> 1);
                    *(bf16x4_t*)&Pw[row * 64 + ((c ^ (row & 7)) << 3) + ((quad & 1) << 2)] = pb;
                }
                sum += __shfl_xor(sum, 16);
                sum += __shfl_xor(sum, 32);
                lrow[qt] += sum;
            }

            // O += P * V^T-frags (V^T from swizzled DMA half-tile)
#pragma unroll
            for (int ks = 0; ks < 2; ks++) {
                bf16x8_t pf[2];
#pragma unroll
                for (int qt = 0; qt < 2; qt++) {
                    int row = qt * 16 + l15;
                    int c = (ks << 2) | quad;
                    pf[qt] = *(const bf16x8_t*)&Pw[row * 64 + ((c ^ (row & 7)) << 3)];
                }
                __builtin_amdgcn_s_setprio(1);
#pragma unroll
                for (int nO = 0; nO < 4; nO++) {
                    int row = nO * 16 + l15;            // hd row within V^T half
                    int c = (ks << 2) | quad;           // 16-B key-chunk within 128-B row
                    bf16x8_t vf = *(const bf16x8_t*)&Vt[cur][row * 64 + ((c ^ (row & 7)) << 3)];
#pragma unroll
                    for (int qt = 0; qt < 2; qt++)
                        o[qt][nO] = __builtin_amdgcn_mfma_f32_16x16x32_bf16(pf[qt], vf, o[qt][nO], 0, 0, 0);
                }
                __builtin_amdgcn_s_setprio(0);
            }
        }

        __syncthreads();  // release buf[cur] readers + drain prefetch into buf[cur^1]
        cur ^= 1;
    }

    const int bb = bh >> 4, hh2 = bh & 15;
    if (qtile >= 8) {
        // split part: write unnormalized O (bf16) + m,l (f32)
        const int pidx = ((bh << 3) + (qtile - 8)) * 2 + (jbeg != 0 ? 1 : 0);
        bf16* Op = Opart + (size_t)pidx * (128 * 64);
        float* mlp = Ml + (size_t)pidx * 256;
#pragma unroll
        for (int qt = 0; qt < 2; qt++) {
            if (quad == 0) {
                mlp[wave * 32 + qt * 16 + l15] = mrow[qt];
                mlp[128 + wave * 32 + qt * 16 + l15] = lrow[qt];
            }
#pragma unroll
            for (int r = 0; r < 4; r++) {
                int row = wave * 32 + qt * 16 + quad * 4 + r;
#pragma unroll
                for (int nO = 0; nO < 4; nO++)
                    Op[row * 64 + nO * 16 + l15] = (bf16)o[qt][nO][r];
            }
        }
    } else {
        // whole tile: normalize and write Ob [B, S, H*64]
#pragma unroll
        for (int qt = 0; qt < 2; qt++) {
#pragma unroll
            for (int r = 0; r < 4; r++) {
                float linv = 1.f / __shfl(lrow[qt], (lane & 48) | (quad * 4 + r));
                int srow = qtile * 128 + wave * 32 + qt * 16 + quad * 4 + r;
#pragma unroll
                for (int nO = 0; nO < 4; nO++)
                    Ob[((size_t)(bb * SS + srow)) * DD + hh2 * HD + nO * 16 + l15] = (bf16)(o[qt][nO][r] * linv);
            }
        }
    }
}

// ---------------- merge two KV-half partials -> Ob (qtiles 8..15) ----------------
__global__ __launch_bounds__(256) void merge_kernel(const bf16* __restrict__ Opart,
                                                    const float* __restrict__ Ml,
                                                    bf16* __restrict__ Ob) {
    const int bh = blockIdx.x >> 3, q8 = blockIdx.x & 7;  // qtile = 8 + q8
    const int p0 = ((bh << 3) + q8) * 2, p1 = p0 + 1;
    const int t = threadIdx.x, row = t >> 1, c0 = (t & 1) * 32;
    float m0 = Ml[p0 * 256 + row], l0 = Ml[p0 * 256 + 128 + row];
    float m1 = Ml[p1 * 256 + row], l1 = Ml[p1 * 256 + 128 + row];
    float M = fmaxf(m0, m1);
    float w0 = exp2f(m0 - M), w1 = exp2f(m1 - M);
    float inv = 1.f / (l0 * w0 + l1 * w1);
    w0 *= inv; w1 *= inv;
    const bf16* O0 = Opart + (size_t)p0 * (128 * 64) + row * 64 + c0;
    const bf16* O1 = Opart + (size_t)p1 * (128 * 64) + row * 64 + c0;
    const int bb = bh >> 4, hh = bh & 15;
    const int srow = (8 + q8) * 128 + row;
    bf16* dst = Ob + ((size_t)(bb * SS + srow)) * DD + hh * HD + c0;
#pragma unroll
    for (int i = 0; i < 4; i++) {
        bf16x8_t a = *(const bf16x8_t*)(O0 + i * 8);
        bf16x8_t b = *(const bf16x8_t*)(O1 + i * 8);
        bf16x8_t r;
#pragma unroll
        for (int jj = 0; jj < 8; jj++)
            r[jj] = (bf16)((float)a[jj] * w0 + (float)b[jj] * w1);
        *(bf16x8_t*)(dst + i * 8) = r;
    }
}

// ---------------- host launcher ----------------
extern "C" void kernel_launch(void* const* d_in, const int* in_sizes, int n_in,
                              void* d_out, int out_size, void* d_ws, size_t ws_size,
                              hipStream_t stream) {
    (void)in_sizes; (void)n_in; (void)out_size; (void)ws_size;
    const float* h  = (const float*)d_in[0];
    const float* Wq = (const float*)d_in[1];
    const float* bq = (const float*)d_in[2];
    const float* Wk = (const float*)d_in[3];
    const float* bk = (const float*)d_in[4];
    const float* Wv = (const float*)d_in[5];
    const float* bv = (const float*)d_in[6];
    const float* Wo = (const float*)d_in[7];
    const float* bo = (const float*)d_in[8];
    float* out = (float*)d_out;

    char* ws = (char*)d_ws;
    bf16* hbf  = (bf16*)(ws);                                  // 8,388,608  h bf16 (dead after gemm_qkv)
    bf16* wqkv = (bf16*)(ws + 8388608);                        // 6,291,456  Wq|Wk|Wv (dead after gemm_qkv)
    bf16* wo   = (bf16*)(ws + 8388608 + 6291456);              // 2,097,152  Wo
    bf16* Qb   = (bf16*)(ws + 16777216);                       // 8,388,608  [B,H,S,64] (scaled)
    bf16* Kb   = (bf16*)(ws + 16777216 + 8388608);             // [B,H,S,64]
    bf16* Vb   = (bf16*)(ws + 16777216 + 2 * 8388608);         // [B,H,64,S]  (transposed!)
    bf16* Ob   = (bf16*)(ws + 16777216 + 3 * 8388608);         // [B,S,H*64]
    // attention scratch reuses the dead cast region:
    bf16*  Opart = (bf16*)(ws);                                // 512 x 128x64 bf16 = 8,388,608
    float* Ml    = (float*)(ws + 8388608);                     // 512 x 256 f32   =   524,288

    cast_all<<<8192, 256, 0, stream>>>(h, Wq, Wk, Wv, Wo, hbf);
    gemm_qkv<<<dim3(32, 24), 256, 0, stream>>>(hbf, wqkv, bq, bk, bv, Qb, Kb, Vb);
    attn_kernel<<<768, 256, 0, stream>>>(Qb, Kb, Vb, Ob, Opart, Ml);
    merge_kernel<<<256, 256, 0, stream>>>(Opart, Ml, Ob);
    gemm_out<<<dim3(64, 8), 256, 0, stream>>>(Ob, wo, bo, out);
}